// Round 2
// baseline (9878.654 us; speedup 1.0000x reference)
//
#include <hip/hip_runtime.h>
#include <math.h>

#define B_   128
#define T_   2048
#define DIN  128
#define H_   256

__device__ __forceinline__ void f4fma(float4& a, float s, const float4& w) {
  a.x = fmaf(s, w.x, a.x);
  a.y = fmaf(s, w.y, a.y);
  a.z = fmaf(s, w.z, a.z);
  a.w = fmaf(s, w.w, a.w);
}

// ===================== phase 1: input projections =====================
// grid: (128*Tc/32, 3), block 256.  Computes xout[R][ct*256+h] for R=b*Tc+tau.
__global__ __launch_bounds__(256, 3) void proj_kernel(
    const float* __restrict__ x,
    const float* __restrict__ Wz, const float* __restrict__ Wr, const float* __restrict__ Wx,
    const float* __restrict__ Bz, const float* __restrict__ Br,
    float* __restrict__ xout, int t0, int Tc)
{
  __shared__ float xs[32 * DIN];    // 16 KB
  __shared__ float ws[32 * H_];     // 32 KB
  const int tid = threadIdx.x;
  const int c0  = tid & 63;         // col group: cols 4*c0..4*c0+3
  const int rg  = tid >> 6;         // row group: rows 8*rg..8*rg+7
  const int rt  = blockIdx.x;
  const int ct  = blockIdx.y;       // 0:Wz 1:Wr 2:Wx
  const float* Wm = (ct == 0) ? Wz : (ct == 1) ? Wr : Wx;

  const int R0   = rt * 32;
  const int bb   = R0 / Tc;         // 32 | Tc, so whole tile is one batch
  const int tau0 = R0 - bb * Tc;
  const float* xsrc = x + ((size_t)bb * T_ + t0 + tau0) * DIN;

  // stage x tile: 32 rows x 128 = 4096 floats, fully coalesced
  #pragma unroll
  for (int u = 0; u < 4; ++u) {
    int id = tid + 256 * u;
    *(float4*)&xs[4 * id] = *(const float4*)&xsrc[4 * id];
  }

  float4 acc[8];
  #pragma unroll
  for (int r = 0; r < 8; ++r) acc[r] = make_float4(0.f, 0.f, 0.f, 0.f);

  for (int ks = 0; ks < DIN; ks += 32) {
    __syncthreads();
    // stage W rows ks..ks+31 (32x256 floats)
    #pragma unroll
    for (int u = 0; u < 8; ++u) {
      int id = tid + 256 * u;                 // float4 index
      int row = id >> 6, col4 = id & 63;
      *(float4*)&ws[4 * id] = *(const float4*)&Wm[(size_t)(ks + row) * H_ + 4 * col4];
    }
    __syncthreads();
    #pragma unroll
    for (int kk = 0; kk < 32; kk += 4) {
      float4 xv[8];
      #pragma unroll
      for (int r = 0; r < 8; ++r)
        xv[r] = *(const float4*)&xs[(8 * rg + r) * DIN + ks + kk];
      #pragma unroll
      for (int u = 0; u < 4; ++u) {
        float4 wv = *(const float4*)&ws[(kk + u) * H_ + 4 * c0];
        #pragma unroll
        for (int r = 0; r < 8; ++r) {
          float s = (u == 0) ? xv[r].x : (u == 1) ? xv[r].y : (u == 2) ? xv[r].z : xv[r].w;
          f4fma(acc[r], s, wv);
        }
      }
    }
  }

  float4 bias = make_float4(0.f, 0.f, 0.f, 0.f);
  if (ct == 0)      bias = *(const float4*)&Bz[4 * c0];
  else if (ct == 1) bias = *(const float4*)&Br[4 * c0];

  #pragma unroll
  for (int r = 0; r < 8; ++r) {
    int R = R0 + 8 * rg + r;
    float4 v = acc[r];
    v.x += bias.x; v.y += bias.y; v.z += bias.z; v.w += bias.w;
    *(float4*)&xout[(size_t)R * 768 + ct * H_ + 4 * c0] = v;
  }
}

// ===================== phase 2: recurrent scan =====================
// 128 blocks (one per batch = one CU), 512 threads (8 waves).
// Resident: Rz rows 0-27 + Uh rows 0-16 in VGPRs, Uh rows 17-31 in LDS.
// Streamed from L2 each step (double-buffered, 9 chunks of 4 rows):
// Rz rows 28-31 + all of Rr (~288 KB/step/block).
// 2 barriers per step.
__global__ __launch_bounds__(512, 2) void scan_kernel(
    const float* __restrict__ xproj,
    const float* __restrict__ Rz, const float* __restrict__ Rr,
    const float* __restrict__ Uh, const float* __restrict__ Bh,
    const float* __restrict__ h0,
    float* __restrict__ hcarry, float* __restrict__ out,
    int t0, int Tc)
{
  extern __shared__ float smem[];
  float* uh_lds = smem;                 // 15*8*256 floats (120 KB): Uh rows k0+17..k0+31
  float* pA = uh_lds + 15 * 8 * H_;     // 512*4  (accZ partials)
  float* pB = pA + 2048;                // 512*4  (accR partials)
  float* pC = pB + 2048;                // 512*4  (accU partials)
  float* hb = pC + 2048;                // 256
  float* xb = hb + H_;                  // 2*768
  // total: 30720 + 3*2048 + 256 + 1536 = 38656 floats = 154,624 B

  const int tid = threadIdx.x;
  const int g   = tid & 63;
  const int kb  = tid >> 6;             // k-block 0..7 (== wave id)
  const int k0  = kb * 32;
  const int g4  = 4 * g;
  const int b   = blockIdx.x;

  const float* xp = xproj + (size_t)b * Tc * 768;
  float* outp = out + ((size_t)b * T_ + t0) * H_;

  // ---- resident weights ----
  float4 wz[28], wu[17];
  #pragma unroll
  for (int i = 0; i < 28; ++i) wz[i] = *(const float4*)&Rz[(size_t)(k0 + i) * H_ + g4];
  #pragma unroll
  for (int i = 0; i < 17; ++i) wu[i] = *(const float4*)&Uh[(size_t)(k0 + i) * H_ + g4];
  #pragma unroll
  for (int i = 0; i < 15; ++i) {
    float4 v = *(const float4*)&Uh[(size_t)(k0 + 17 + i) * H_ + g4];
    *(float4*)&uh_lds[(kb * 15 + i) * H_ + g4] = v;   // each thread reads back only its own
  }

  float bh_j = 0.f;
  if (tid < H_) {
    hb[tid] = (t0 == 0) ? h0[b * H_ + tid] : hcarry[b * H_ + tid];
    bh_j = Bh[tid];
  }
  // prefetch x slice for tau=0
  float4 xcur = make_float4(0.f, 0.f, 0.f, 0.f);
  if (tid < 192) xcur = *(const float4*)&xp[4 * tid];
  __syncthreads();
  if (tid < 192) *(float4*)&xb[4 * tid] = xcur;   // read first at s1 of step 0

  int parity = 0;

  for (int tau = 0; tau < Tc; ++tau) {
    int blind = 0;
    asm volatile("" : "+v"(blind));          // keep streamed loads loop-variant (no hoist)
    const float* RzB = Rz + blind;
    const float* RrB = Rr + blind;

    // x prefetch for tau+1
    float4 xnext = make_float4(0.f, 0.f, 0.f, 0.f);
    const bool dox = (tid < 192) && (tau + 1 < Tc);
    if (dox) xnext = *(const float4*)&xp[(size_t)(tau + 1) * 768 + 4 * tid];

    float4 bufA[4], bufB[4];
    #pragma unroll
    for (int i = 0; i < 4; ++i) bufA[i] = *(const float4*)&RzB[(size_t)(k0 + 28 + i) * H_ + g4]; // c0
    #pragma unroll
    for (int i = 0; i < 4; ++i) bufB[i] = *(const float4*)&RrB[(size_t)(k0 + i) * H_ + g4];      // c1

    float4 accZ = make_float4(0.f,0.f,0.f,0.f);
    float4 accR = make_float4(0.f,0.f,0.f,0.f);
    float4 accU = make_float4(0.f,0.f,0.f,0.f);

    // seg0: Z rows 0-6 | consume c0 (Rz 28-31) | load c2 (Rr 4-7)
    #pragma unroll
    for (int i = 0; i < 7; ++i) f4fma(accZ, hb[k0 + i], wz[i]);
    #pragma unroll
    for (int i = 0; i < 4; ++i) f4fma(accZ, hb[k0 + 28 + i], bufA[i]);
    #pragma unroll
    for (int i = 0; i < 4; ++i) bufA[i] = *(const float4*)&RrB[(size_t)(k0 + 4 + i) * H_ + g4];
    // seg1: Z rows 7-13 | consume c1 (Rr 0-3) | load c3 (Rr 8-11)
    #pragma unroll
    for (int i = 7; i < 14; ++i) f4fma(accZ, hb[k0 + i], wz[i]);
    #pragma unroll
    for (int i = 0; i < 4; ++i) f4fma(accR, hb[k0 + i], bufB[i]);
    #pragma unroll
    for (int i = 0; i < 4; ++i) bufB[i] = *(const float4*)&RrB[(size_t)(k0 + 8 + i) * H_ + g4];
    // seg2: Z rows 14-20 | consume c2 (Rr 4-7) | load c4 (Rr 12-15)
    #pragma unroll
    for (int i = 14; i < 21; ++i) f4fma(accZ, hb[k0 + i], wz[i]);
    #pragma unroll
    for (int i = 0; i < 4; ++i) f4fma(accR, hb[k0 + 4 + i], bufA[i]);
    #pragma unroll
    for (int i = 0; i < 4; ++i) bufA[i] = *(const float4*)&RrB[(size_t)(k0 + 12 + i) * H_ + g4];
    // seg3: Z rows 21-27 | consume c3 (Rr 8-11) | load c5 (Rr 16-19)
    #pragma unroll
    for (int i = 21; i < 28; ++i) f4fma(accZ, hb[k0 + i], wz[i]);
    #pragma unroll
    for (int i = 0; i < 4; ++i) f4fma(accR, hb[k0 + 8 + i], bufB[i]);
    #pragma unroll
    for (int i = 0; i < 4; ++i) bufB[i] = *(const float4*)&RrB[(size_t)(k0 + 16 + i) * H_ + g4];
    // seg4: U-reg rows 0-8 | consume c4 (Rr 12-15) | load c6 (Rr 20-23)
    #pragma unroll
    for (int i = 0; i < 9; ++i) f4fma(accU, hb[k0 + i], wu[i]);
    #pragma unroll
    for (int i = 0; i < 4; ++i) f4fma(accR, hb[k0 + 12 + i], bufA[i]);
    #pragma unroll
    for (int i = 0; i < 4; ++i) bufA[i] = *(const float4*)&RrB[(size_t)(k0 + 20 + i) * H_ + g4];
    // seg5: U-reg rows 9-16 | consume c5 (Rr 16-19) | load c7 (Rr 24-27)
    #pragma unroll
    for (int i = 9; i < 17; ++i) f4fma(accU, hb[k0 + i], wu[i]);
    #pragma unroll
    for (int i = 0; i < 4; ++i) f4fma(accR, hb[k0 + 16 + i], bufB[i]);
    #pragma unroll
    for (int i = 0; i < 4; ++i) bufB[i] = *(const float4*)&RrB[(size_t)(k0 + 24 + i) * H_ + g4];
    // seg6: U-lds rows 0-7 (global rows k0+17..k0+24) | consume c6 (Rr 20-23) | load c8 (Rr 28-31)
    #pragma unroll
    for (int i = 0; i < 8; ++i) {
      float4 w = *(const float4*)&uh_lds[(kb * 15 + i) * H_ + g4];
      f4fma(accU, hb[k0 + 17 + i], w);
    }
    #pragma unroll
    for (int i = 0; i < 4; ++i) f4fma(accR, hb[k0 + 20 + i], bufA[i]);
    #pragma unroll
    for (int i = 0; i < 4; ++i) bufA[i] = *(const float4*)&RrB[(size_t)(k0 + 28 + i) * H_ + g4];
    // seg7: U-lds rows 8-14 (global rows k0+25..k0+31) | consume c7 (Rr 24-27)
    #pragma unroll
    for (int i = 8; i < 15; ++i) {
      float4 w = *(const float4*)&uh_lds[(kb * 15 + i) * H_ + g4];
      f4fma(accU, hb[k0 + 17 + i], w);
    }
    #pragma unroll
    for (int i = 0; i < 4; ++i) f4fma(accR, hb[k0 + 24 + i], bufB[i]);
    // seg8: consume c8 (Rr 28-31)
    #pragma unroll
    for (int i = 0; i < 4; ++i) f4fma(accR, hb[k0 + 28 + i], bufA[i]);

    // publish all partials + next-step x, ONE barrier
    *(float4*)&pA[4 * tid] = accZ;
    *(float4*)&pB[4 * tid] = accR;
    *(float4*)&pC[4 * tid] = accU;
    if (dox) *(float4*)&xb[(parity ^ 1) * 768 + 4 * tid] = xnext;
    __syncthreads();                       // s1

    if (tid < H_) {
      const int j = tid;
      float sz = xb[parity * 768 + j];
      float sr = xb[parity * 768 + H_ + j];
      float su = 0.f;
      #pragma unroll
      for (int q = 0; q < 8; ++q) {
        sz += pA[q * 256 + j];             // pA[4*t + c] with t=q*64+(j>>2), c=j&3  ==  q*256+j
        sr += pB[q * 256 + j];
        su += pC[q * 256 + j];
      }
      float zt = 1.f / (1.f + expf(-sz));
      float rt = 1.f / (1.f + expf(-sr));
      float zi = xb[parity * 768 + 2 * H_ + j] + rt * su;
      float a = fabsf(zi);
      float relu_v = fmaxf(a + bh_j, 0.f);
      float mr = (zi / a) * relu_v;        // modReLU (faithful, incl. 0/0 -> NaN like ref)
      float hold = hb[j];
      float hn = zt * hold + (1.f - zt) * mr;
      outp[(size_t)tau * H_ + j] = hn;
      hb[j] = hn;
    }
    __syncthreads();                       // s2
    parity ^= 1;
  }

  if (tid < H_) hcarry[b * H_ + tid] = hb[tid];
}

// ===================== launcher =====================
extern "C" void kernel_launch(void* const* d_in, const int* in_sizes, int n_in,
                              void* d_out, int out_size, void* d_ws, size_t ws_size,
                              hipStream_t stream)
{
  const float* x  = (const float*)d_in[0];
  const float* h0 = (const float*)d_in[1];
  const float* Wz = (const float*)d_in[2];
  const float* Wr = (const float*)d_in[3];
  const float* Wx = (const float*)d_in[4];
  const float* Uh = (const float*)d_in[5];
  const float* Rz = (const float*)d_in[6];
  const float* Rr = (const float*)d_in[7];
  const float* Bz = (const float*)d_in[8];
  const float* Br = (const float*)d_in[9];
  const float* Bh = (const float*)d_in[10];
  float* out = (float*)d_out;

  float* hcarry = (float*)d_ws;                  // 128*256 floats (128 KB)
  float* xproj  = (float*)d_ws + 32768;

  // pick largest chunk of T that fits in workspace (all candidates divide 2048,
  // and are multiples of 32 so a proj tile never spans two batch rows)
  int Tc = 32;
  const int cands[7] = {2048, 1024, 512, 256, 128, 64, 32};
  for (int i = 0; i < 7; ++i) {
    size_t need = 131072 + (size_t)cands[i] * 128 * 768 * 4;
    if (need <= ws_size) { Tc = cands[i]; break; }
  }

  const int SMEM = (15 * 8 * 256 + 3 * 2048 + 256 + 2 * 768) * 4;  // 154,624 B
  (void)hipFuncSetAttribute((const void*)scan_kernel,
                            hipFuncAttributeMaxDynamicSharedMemorySize, SMEM);

  const int nch = T_ / Tc;
  for (int c = 0; c < nch; ++c) {
    int t0 = c * Tc;
    dim3 g1(128 * Tc / 32, 3);
    proj_kernel<<<g1, 256, 0, stream>>>(x, Wz, Wr, Wx, Bz, Br, xproj, t0, Tc);
    scan_kernel<<<128, 512, SMEM, stream>>>(xproj, Rz, Rr, Uh, Bh, h0,
                                            hcarry, out, t0, Tc);
  }
}